// Round 6
// baseline (154.703 us; speedup 1.0000x reference)
//
#include <hip/hip_runtime.h>

#define HIDDEN 128

typedef _Float16 f16x8 __attribute__((ext_vector_type(8)));
typedef _Float16 f16x4 __attribute__((ext_vector_type(4)));
typedef _Float16 f16x2 __attribute__((ext_vector_type(2)));
typedef __fp16   fp16v2 __attribute__((ext_vector_type(2)));  // builtin ABI type
typedef float f32x4 __attribute__((ext_vector_type(4)));

// ---------------------------------------------------------------------------
// Kernel 0: pack W1 (fp32, (256,128)) into fp16 MFMA fragments.
// Bmat (K=128, N=256): Bmat[k][n] = n<128 ? W1[k][n] : W1[128+k][n-128]
// Wpk[((jt*4+kt)*64 + lane)*8 + j] = Bmat[kt*32+(lane>>4)*8+j][jt*16+(lane&15)]
// Serves as A-operand fragment (A = Bmat^T): lane holds A[lane&15][(lane>>4)*8+j].
// ---------------------------------------------------------------------------
__global__ __launch_bounds__(64) void prep_w(const float* __restrict__ W1,
                                             _Float16* __restrict__ Wpk) {
  const int blk = blockIdx.x;        // 0..63 = jt*4 + kt
  const int jt = blk >> 2;
  const int kt = blk & 3;
  const int lane = threadIdx.x;      // 0..63
  const int col = jt * 16 + (lane & 15);         // feature 0..255
  const int kbase = kt * 32 + (lane >> 4) * 8;   // 0..120
  f16x8 v;
#pragma unroll
  for (int j = 0; j < 8; ++j) {
    const int k = kbase + j;
    const float w = (col < HIDDEN) ? W1[k * HIDDEN + col]
                                   : W1[(HIDDEN + k) * HIDDEN + (col - HIDDEN)];
    v[j] = (_Float16)w;
  }
  *reinterpret_cast<f16x8*>(Wpk + ((size_t)blk * 64 + lane) * 8) = v;
}

// ---------------------------------------------------------------------------
// Kernel 1 (v5): persistent grid-stride MFMA GEMM, depth-1 prefetch,
// 5 waves/SIMD occupancy (1280 blocks, launch_bounds(256,5)).
// D[feat][node] = Wt @ h^T per 16-node tile; W-fragments + bias in VGPRs.
// ---------------------------------------------------------------------------
__global__ __launch_bounds__(256, 5) void gemm_mfma_v5(
    const float* __restrict__ h, const _Float16* __restrict__ Wpk,
    const float* __restrict__ b1, _Float16* __restrict__ Af,
    _Float16* __restrict__ Bf, int n_nodes, int ntiles) {
  const int lane = threadIdx.x & 63;
  const int wave = threadIdx.x >> 6;
  const int nl = lane & 15;
  const int kgrp = lane >> 4;
  const int jt0 = wave * 4;

  // Persistent W fragments: 16 x f16x8 (64 VGPRs), L2-resident source.
  const f16x8* wp = reinterpret_cast<const f16x8*>(Wpk);
  f16x8 wfrag[4][4];
#pragma unroll
  for (int j4 = 0; j4 < 4; ++j4)
#pragma unroll
    for (int kt = 0; kt < 4; ++kt)
      wfrag[j4][kt] = wp[((jt0 + j4) * 4 + kt) * 64 + lane];

  // Persistent bias (A-half only).
  f32x4 binit[4];
#pragma unroll
  for (int j4 = 0; j4 < 4; ++j4) {
    const int jt = jt0 + j4;
    if (jt < 8) {
      binit[j4] = *reinterpret_cast<const f32x4*>(b1 + jt * 16 + kgrp * 4);
    } else {
      binit[j4][0] = 0.f; binit[j4][1] = 0.f; binit[j4][2] = 0.f; binit[j4][3] = 0.f;
    }
  }

  float4 buf[8];     // raw fp32 loads for the NEXT tile (in flight)
  f16x8 hfrag[4];    // converted fragments for the CURRENT tile

  auto LOAD = [&](int tile) {
    int node = tile * 16 + nl;
    if (node >= n_nodes) node = 0;  // clamp; stores are guarded
    const float4* hp = reinterpret_cast<const float4*>(h) +
                       (size_t)node * 32 + kgrp * 2;
#pragma unroll
    for (int kt = 0; kt < 4; ++kt) {
      buf[kt * 2]     = hp[kt * 8];
      buf[kt * 2 + 1] = hp[kt * 8 + 1];
    }
  };

  auto CVT = [&]() {
#pragma unroll
    for (int kt = 0; kt < 4; ++kt) {
      const float4 v0 = buf[kt * 2];
      const float4 v1 = buf[kt * 2 + 1];
      const fp16v2 p0 = __builtin_amdgcn_cvt_pkrtz(v0.x, v0.y);
      const fp16v2 p1 = __builtin_amdgcn_cvt_pkrtz(v0.z, v0.w);
      const fp16v2 p2 = __builtin_amdgcn_cvt_pkrtz(v1.x, v1.y);
      const fp16v2 p3 = __builtin_amdgcn_cvt_pkrtz(v1.z, v1.w);
      hfrag[kt][0] = (_Float16)p0[0]; hfrag[kt][1] = (_Float16)p0[1];
      hfrag[kt][2] = (_Float16)p1[0]; hfrag[kt][3] = (_Float16)p1[1];
      hfrag[kt][4] = (_Float16)p2[0]; hfrag[kt][5] = (_Float16)p2[1];
      hfrag[kt][6] = (_Float16)p3[0]; hfrag[kt][7] = (_Float16)p3[1];
    }
  };

  auto COMPUTE_STORE = [&](int tile) {
    f32x4 acc[4];
#pragma unroll
    for (int j4 = 0; j4 < 4; ++j4) acc[j4] = binit[j4];
#pragma unroll
    for (int kt = 0; kt < 4; ++kt)
#pragma unroll
      for (int j4 = 0; j4 < 4; ++j4)
        acc[j4] = __builtin_amdgcn_mfma_f32_16x16x32_f16(
            wfrag[j4][kt], hfrag[kt], acc[j4], 0, 0, 0);
    const int node = tile * 16 + nl;
    if (node < n_nodes) {
#pragma unroll
      for (int j4 = 0; j4 < 4; ++j4) {
        const int jt = jt0 + j4;
        _Float16* dst = ((jt < 8) ? Af : Bf) +
                        (size_t)node * HIDDEN + (jt & 7) * 16 + kgrp * 4;
        f16x4 v;
        v[0] = (_Float16)acc[j4][0];
        v[1] = (_Float16)acc[j4][1];
        v[2] = (_Float16)acc[j4][2];
        v[3] = (_Float16)acc[j4][3];
        *reinterpret_cast<f16x4*>(dst) = v;
      }
    }
  };

  const int stride = gridDim.x;
  int tile = blockIdx.x;
  if (tile >= ntiles) return;

  LOAD(tile);
  CVT();
  int next = tile + stride;
  if (next < ntiles) LOAD(next);

  while (true) {
    COMPUTE_STORE(tile);
    if (next >= ntiles) break;
    CVT();
    const int next2 = next + stride;
    if (next2 < ntiles) LOAD(next2);
    tile = next;
    next = next2;
  }
}

// ---------------------------------------------------------------------------
// Kernel 2 (v4): per edge, score = relu(A[src] + B[dst]) . W2 + b2
// One wave per 16 edges; lane i holds f16x2 (4B) of each 256B row.
// 32-bit offsets (1 VALU addr/load), packed fp16 add/relu + fdot2.
// Merged butterfly reduction: lanes 0..15 end with the 16 edge scores.
// ---------------------------------------------------------------------------
__global__ __launch_bounds__(256) void edge_score_v4(
    const int* __restrict__ ei, const _Float16* __restrict__ Af,
    const _Float16* __restrict__ Bf, const float* __restrict__ W2,
    const float* __restrict__ b2, float* __restrict__ out, int n_edges) {
  const int wid = (int)((blockIdx.x * 256 + threadIdx.x) >> 6);
  const int lane = threadIdx.x & 63;
  const int e0 = wid * 16;
  if (e0 >= n_edges) return;

  int srcs[16], dsts[16];
#pragma unroll
  for (int k = 0; k < 16; ++k) {
    srcs[k] = ei[e0 + k];
    dsts[k] = ei[n_edges + e0 + k];
  }

  const char* Afc = (const char*)Af;
  const char* Bfc = (const char*)Bf;
  const unsigned int loff = (unsigned int)(lane << 2);

  f16x2 av[16], bv[16];
#pragma unroll
  for (int k = 0; k < 16; ++k) {
    const unsigned int off = ((unsigned int)srcs[k] << 8) + loff;
    av[k] = *reinterpret_cast<const f16x2*>(Afc + off);
  }
#pragma unroll
  for (int k = 0; k < 16; ++k) {
    const unsigned int off = ((unsigned int)dsts[k] << 8) + loff;
    bv[k] = *reinterpret_cast<const f16x2*>(Bfc + off);
  }

  const float2 w2v = reinterpret_cast<const float2*>(W2)[lane];
  const fp16v2 w2h = __builtin_amdgcn_cvt_pkrtz(w2v.x, w2v.y);
  const _Float16 h0 = (_Float16)0.f;

  float p[16];
#pragma unroll
  for (int k = 0; k < 16; ++k) {
    f16x2 s = av[k] + bv[k];                 // v_pk_add_f16
    s[0] = s[0] > h0 ? s[0] : h0;            // pk max vs 0
    s[1] = s[1] > h0 ? s[1] : h0;
    p[k] = __builtin_amdgcn_fdot2(__builtin_bit_cast(fp16v2, s), w2h, 0.f, false);
  }

  auto mrg = [&](float a, float b, int off) {
    const float as = a + __shfl_xor(a, off, 64);
    const float bs = b + __shfl_xor(b, off, 64);
    return (lane & off) ? bs : as;
  };
  float q[8];
#pragma unroll
  for (int i = 0; i < 8; ++i) q[i] = mrg(p[2 * i], p[2 * i + 1], 1);
  float r[4];
#pragma unroll
  for (int i = 0; i < 4; ++i) r[i] = mrg(q[2 * i], q[2 * i + 1], 2);
  float s2[2];
#pragma unroll
  for (int i = 0; i < 2; ++i) s2[i] = mrg(r[2 * i], r[2 * i + 1], 4);
  float t = mrg(s2[0], s2[1], 8);
  t += __shfl_xor(t, 16, 64);
  t += __shfl_xor(t, 32, 64);

  if (lane < 16 && e0 + lane < n_edges) out[e0 + lane] = t + b2[0];
}

// ---------------------------------------------------------------------------
// Fallback (ws too small): fused fp32 per-edge compute.
// ---------------------------------------------------------------------------
__global__ __launch_bounds__(256) void fused_fallback(
    const float* __restrict__ h, const int* __restrict__ ei,
    const float* __restrict__ W1, const float* __restrict__ b1,
    const float* __restrict__ W2, const float* __restrict__ b2,
    float* __restrict__ out, int n_edges) {
  const int e = (int)((blockIdx.x * 256 + threadIdx.x) >> 6);
  const int lane = threadIdx.x & 63;
  if (e >= n_edges) return;
  const int src = ei[e], dst = ei[n_edges + e];
  const float* hs = h + (size_t)src * HIDDEN;
  const float* hd = h + (size_t)dst * HIDDEN;
  float acc0 = b1[lane], acc1 = b1[lane + 64];
  for (int k = 0; k < HIDDEN; ++k) {
    const float s = hs[k], d = hd[k];
    acc0 = fmaf(s, W1[k * HIDDEN + lane], acc0);
    acc0 = fmaf(d, W1[(k + HIDDEN) * HIDDEN + lane], acc0);
    acc1 = fmaf(s, W1[k * HIDDEN + lane + 64], acc1);
    acc1 = fmaf(d, W1[(k + HIDDEN) * HIDDEN + lane + 64], acc1);
  }
  acc0 = acc0 > 0.f ? acc0 : 0.f;
  acc1 = acc1 > 0.f ? acc1 : 0.f;
  float p = fmaf(acc0, W2[lane], acc1 * W2[lane + 64]);
#pragma unroll
  for (int off = 32; off >= 1; off >>= 1) p += __shfl_down(p, off, 64);
  if (lane == 0) out[e] = p + b2[0];
}

extern "C" void kernel_launch(void* const* d_in, const int* in_sizes, int n_in,
                              void* d_out, int out_size, void* d_ws, size_t ws_size,
                              hipStream_t stream) {
  const float* h  = (const float*)d_in[0];
  const int*   ei = (const int*)d_in[1];
  const float* W1 = (const float*)d_in[2];
  const float* b1 = (const float*)d_in[3];
  const float* W2 = (const float*)d_in[4];
  const float* b2 = (const float*)d_in[5];
  float* out = (float*)d_out;

  const int n_nodes = in_sizes[0] / HIDDEN;  // 100000
  const int n_edges = in_sizes[1] / 2;       // 640000

  const size_t wpk_halfs  = 64 * 64 * 8;                       // 32768
  const size_t proj_halfs = (size_t)n_nodes * HIDDEN;          // 12.8M
  const size_t need = (wpk_halfs + 2 * proj_halfs) * sizeof(_Float16);

  if (ws_size >= need) {
    _Float16* Wpk = (_Float16*)d_ws;
    _Float16* A   = Wpk + wpk_halfs;
    _Float16* B   = A + proj_halfs;

    prep_w<<<64, 64, 0, stream>>>(W1, Wpk);

    const int ntiles = (n_nodes + 15) / 16;       // 6250
    const int gblocks = ntiles < 1280 ? ntiles : 1280;
    gemm_mfma_v5<<<gblocks, 256, 0, stream>>>(h, Wpk, b1, A, B, n_nodes, ntiles);

    const int nwaves = (n_edges + 15) / 16;
    const int eblocks = (nwaves + 3) / 4;
    edge_score_v4<<<eblocks, 256, 0, stream>>>(ei, A, B, W2, b2, out, n_edges);
  } else {
    const int eblocks = (n_edges + 3) / 4;
    fused_fallback<<<eblocks, 256, 0, stream>>>(h, ei, W1, b1, W2, b2, out, n_edges);
  }
}

// Round 7
// 128.593 us; speedup vs baseline: 1.2030x; 1.2030x over previous
//
#include <hip/hip_runtime.h>

#define HIDDEN 128

typedef _Float16 f16x8 __attribute__((ext_vector_type(8)));
typedef _Float16 f16x4 __attribute__((ext_vector_type(4)));
typedef _Float16 f16x2 __attribute__((ext_vector_type(2)));
typedef __fp16   fp16v2 __attribute__((ext_vector_type(2)));  // builtin ABI type
typedef float f32x4 __attribute__((ext_vector_type(4)));

// ---------------------------------------------------------------------------
// Kernel 0: pack W1 (fp32, (256,128)) into fp16 MFMA fragments.
// Bmat (K=128, N=256): Bmat[k][n] = n<128 ? W1[k][n] : W1[128+k][n-128]
// Wpk[((jt*4+kt)*64 + lane)*8 + j] = Bmat[kt*32+(lane>>4)*8+j][jt*16+(lane&15)]
// Serves as A-operand fragment (A = Bmat^T): lane holds A[lane&15][(lane>>4)*8+j].
// ---------------------------------------------------------------------------
__global__ __launch_bounds__(64) void prep_w(const float* __restrict__ W1,
                                             _Float16* __restrict__ Wpk) {
  const int blk = blockIdx.x;        // 0..63 = jt*4 + kt
  const int jt = blk >> 2;
  const int kt = blk & 3;
  const int lane = threadIdx.x;      // 0..63
  const int col = jt * 16 + (lane & 15);         // feature 0..255
  const int kbase = kt * 32 + (lane >> 4) * 8;   // 0..120
  f16x8 v;
#pragma unroll
  for (int j = 0; j < 8; ++j) {
    const int k = kbase + j;
    const float w = (col < HIDDEN) ? W1[k * HIDDEN + col]
                                   : W1[(HIDDEN + k) * HIDDEN + (col - HIDDEN)];
    v[j] = (_Float16)w;
  }
  *reinterpret_cast<f16x8*>(Wpk + ((size_t)blk * 64 + lane) * 8) = v;
}

// ---------------------------------------------------------------------------
// Kernel 1 (v6): persistent grid-stride MFMA GEMM, depth-1 prefetch.
// launch_bounds(256,4): VGPR cap 128 >= ~84 needed -> NO SPILLS (v5 post-
// mortem: the (256,5) hint forced 48 VGPRs and 350MB of scratch traffic).
// Grid 1280 blocks (5/CU) for occupancy; VGPR count allows 6 waves/SIMD.
// D[feat][node] = Wt @ h^T per 16-node tile; W-fragments + bias in VGPRs.
// ---------------------------------------------------------------------------
__global__ __launch_bounds__(256, 4) void gemm_mfma_v6(
    const float* __restrict__ h, const _Float16* __restrict__ Wpk,
    const float* __restrict__ b1, _Float16* __restrict__ Af,
    _Float16* __restrict__ Bf, int n_nodes, int ntiles) {
  const int lane = threadIdx.x & 63;
  const int wave = threadIdx.x >> 6;
  const int nl = lane & 15;
  const int kgrp = lane >> 4;
  const int jt0 = wave * 4;

  // Persistent W fragments: 16 x f16x8 (64 VGPRs), L2-resident source.
  const f16x8* wp = reinterpret_cast<const f16x8*>(Wpk);
  f16x8 wfrag[4][4];
#pragma unroll
  for (int j4 = 0; j4 < 4; ++j4)
#pragma unroll
    for (int kt = 0; kt < 4; ++kt)
      wfrag[j4][kt] = wp[((jt0 + j4) * 4 + kt) * 64 + lane];

  // Persistent bias (A-half only).
  f32x4 binit[4];
#pragma unroll
  for (int j4 = 0; j4 < 4; ++j4) {
    const int jt = jt0 + j4;
    if (jt < 8) {
      binit[j4] = *reinterpret_cast<const f32x4*>(b1 + jt * 16 + kgrp * 4);
    } else {
      binit[j4][0] = 0.f; binit[j4][1] = 0.f; binit[j4][2] = 0.f; binit[j4][3] = 0.f;
    }
  }

  float4 buf[8];     // raw fp32 loads for the NEXT tile (in flight)
  f16x8 hfrag[4];    // converted fragments for the CURRENT tile

  auto LOAD = [&](int tile) {
    int node = tile * 16 + nl;
    if (node >= n_nodes) node = 0;  // clamp; stores are guarded
    const float4* hp = reinterpret_cast<const float4*>(h) +
                       (size_t)node * 32 + kgrp * 2;
#pragma unroll
    for (int kt = 0; kt < 4; ++kt) {
      buf[kt * 2]     = hp[kt * 8];
      buf[kt * 2 + 1] = hp[kt * 8 + 1];
    }
  };

  auto CVT = [&]() {
#pragma unroll
    for (int kt = 0; kt < 4; ++kt) {
      const float4 v0 = buf[kt * 2];
      const float4 v1 = buf[kt * 2 + 1];
      const fp16v2 p0 = __builtin_amdgcn_cvt_pkrtz(v0.x, v0.y);
      const fp16v2 p1 = __builtin_amdgcn_cvt_pkrtz(v0.z, v0.w);
      const fp16v2 p2 = __builtin_amdgcn_cvt_pkrtz(v1.x, v1.y);
      const fp16v2 p3 = __builtin_amdgcn_cvt_pkrtz(v1.z, v1.w);
      hfrag[kt][0] = (_Float16)p0[0]; hfrag[kt][1] = (_Float16)p0[1];
      hfrag[kt][2] = (_Float16)p1[0]; hfrag[kt][3] = (_Float16)p1[1];
      hfrag[kt][4] = (_Float16)p2[0]; hfrag[kt][5] = (_Float16)p2[1];
      hfrag[kt][6] = (_Float16)p3[0]; hfrag[kt][7] = (_Float16)p3[1];
    }
  };

  auto COMPUTE_STORE = [&](int tile) {
    f32x4 acc[4];
#pragma unroll
    for (int j4 = 0; j4 < 4; ++j4) acc[j4] = binit[j4];
#pragma unroll
    for (int kt = 0; kt < 4; ++kt)
#pragma unroll
      for (int j4 = 0; j4 < 4; ++j4)
        acc[j4] = __builtin_amdgcn_mfma_f32_16x16x32_f16(
            wfrag[j4][kt], hfrag[kt], acc[j4], 0, 0, 0);
    const int node = tile * 16 + nl;
    if (node < n_nodes) {
#pragma unroll
      for (int j4 = 0; j4 < 4; ++j4) {
        const int jt = jt0 + j4;
        _Float16* dst = ((jt < 8) ? Af : Bf) +
                        (size_t)node * HIDDEN + (jt & 7) * 16 + kgrp * 4;
        f16x4 v;
        v[0] = (_Float16)acc[j4][0];
        v[1] = (_Float16)acc[j4][1];
        v[2] = (_Float16)acc[j4][2];
        v[3] = (_Float16)acc[j4][3];
        *reinterpret_cast<f16x4*>(dst) = v;
      }
    }
  };

  const int stride = gridDim.x;
  int tile = blockIdx.x;
  if (tile >= ntiles) return;

  LOAD(tile);
  CVT();
  int next = tile + stride;
  if (next < ntiles) LOAD(next);

  while (true) {
    COMPUTE_STORE(tile);
    if (next >= ntiles) break;
    CVT();
    const int next2 = next + stride;
    if (next2 < ntiles) LOAD(next2);
    tile = next;
    next = next2;
  }
}

// ---------------------------------------------------------------------------
// Kernel 2 (v4): per edge, score = relu(A[src] + B[dst]) . W2 + b2
// One wave per 16 edges; lane i holds f16x2 (4B) of each 256B row.
// 32-bit offsets (1 VALU addr/load), packed fp16 add/relu + fdot2.
// Merged butterfly reduction: lanes 0..15 end with the 16 edge scores.
// ---------------------------------------------------------------------------
__global__ __launch_bounds__(256) void edge_score_v4(
    const int* __restrict__ ei, const _Float16* __restrict__ Af,
    const _Float16* __restrict__ Bf, const float* __restrict__ W2,
    const float* __restrict__ b2, float* __restrict__ out, int n_edges) {
  const int wid = (int)((blockIdx.x * 256 + threadIdx.x) >> 6);
  const int lane = threadIdx.x & 63;
  const int e0 = wid * 16;
  if (e0 >= n_edges) return;

  int srcs[16], dsts[16];
#pragma unroll
  for (int k = 0; k < 16; ++k) {
    srcs[k] = ei[e0 + k];
    dsts[k] = ei[n_edges + e0 + k];
  }

  const char* Afc = (const char*)Af;
  const char* Bfc = (const char*)Bf;
  const unsigned int loff = (unsigned int)(lane << 2);

  f16x2 av[16], bv[16];
#pragma unroll
  for (int k = 0; k < 16; ++k) {
    const unsigned int off = ((unsigned int)srcs[k] << 8) + loff;
    av[k] = *reinterpret_cast<const f16x2*>(Afc + off);
  }
#pragma unroll
  for (int k = 0; k < 16; ++k) {
    const unsigned int off = ((unsigned int)dsts[k] << 8) + loff;
    bv[k] = *reinterpret_cast<const f16x2*>(Bfc + off);
  }

  const float2 w2v = reinterpret_cast<const float2*>(W2)[lane];
  const fp16v2 w2h = __builtin_amdgcn_cvt_pkrtz(w2v.x, w2v.y);
  const _Float16 h0 = (_Float16)0.f;

  float p[16];
#pragma unroll
  for (int k = 0; k < 16; ++k) {
    f16x2 s = av[k] + bv[k];                 // v_pk_add_f16
    s[0] = s[0] > h0 ? s[0] : h0;            // pk max vs 0
    s[1] = s[1] > h0 ? s[1] : h0;
    p[k] = __builtin_amdgcn_fdot2(__builtin_bit_cast(fp16v2, s), w2h, 0.f, false);
  }

  auto mrg = [&](float a, float b, int off) {
    const float as = a + __shfl_xor(a, off, 64);
    const float bs = b + __shfl_xor(b, off, 64);
    return (lane & off) ? bs : as;
  };
  float q[8];
#pragma unroll
  for (int i = 0; i < 8; ++i) q[i] = mrg(p[2 * i], p[2 * i + 1], 1);
  float r[4];
#pragma unroll
  for (int i = 0; i < 4; ++i) r[i] = mrg(q[2 * i], q[2 * i + 1], 2);
  float s2[2];
#pragma unroll
  for (int i = 0; i < 2; ++i) s2[i] = mrg(r[2 * i], r[2 * i + 1], 4);
  float t = mrg(s2[0], s2[1], 8);
  t += __shfl_xor(t, 16, 64);
  t += __shfl_xor(t, 32, 64);

  if (lane < 16 && e0 + lane < n_edges) out[e0 + lane] = t + b2[0];
}

// ---------------------------------------------------------------------------
// Fallback (ws too small): fused fp32 per-edge compute.
// ---------------------------------------------------------------------------
__global__ __launch_bounds__(256) void fused_fallback(
    const float* __restrict__ h, const int* __restrict__ ei,
    const float* __restrict__ W1, const float* __restrict__ b1,
    const float* __restrict__ W2, const float* __restrict__ b2,
    float* __restrict__ out, int n_edges) {
  const int e = (int)((blockIdx.x * 256 + threadIdx.x) >> 6);
  const int lane = threadIdx.x & 63;
  if (e >= n_edges) return;
  const int src = ei[e], dst = ei[n_edges + e];
  const float* hs = h + (size_t)src * HIDDEN;
  const float* hd = h + (size_t)dst * HIDDEN;
  float acc0 = b1[lane], acc1 = b1[lane + 64];
  for (int k = 0; k < HIDDEN; ++k) {
    const float s = hs[k], d = hd[k];
    acc0 = fmaf(s, W1[k * HIDDEN + lane], acc0);
    acc0 = fmaf(d, W1[(k + HIDDEN) * HIDDEN + lane], acc0);
    acc1 = fmaf(s, W1[k * HIDDEN + lane + 64], acc1);
    acc1 = fmaf(d, W1[(k + HIDDEN) * HIDDEN + lane + 64], acc1);
  }
  acc0 = acc0 > 0.f ? acc0 : 0.f;
  acc1 = acc1 > 0.f ? acc1 : 0.f;
  float p = fmaf(acc0, W2[lane], acc1 * W2[lane + 64]);
#pragma unroll
  for (int off = 32; off >= 1; off >>= 1) p += __shfl_down(p, off, 64);
  if (lane == 0) out[e] = p + b2[0];
}

extern "C" void kernel_launch(void* const* d_in, const int* in_sizes, int n_in,
                              void* d_out, int out_size, void* d_ws, size_t ws_size,
                              hipStream_t stream) {
  const float* h  = (const float*)d_in[0];
  const int*   ei = (const int*)d_in[1];
  const float* W1 = (const float*)d_in[2];
  const float* b1 = (const float*)d_in[3];
  const float* W2 = (const float*)d_in[4];
  const float* b2 = (const float*)d_in[5];
  float* out = (float*)d_out;

  const int n_nodes = in_sizes[0] / HIDDEN;  // 100000
  const int n_edges = in_sizes[1] / 2;       // 640000

  const size_t wpk_halfs  = 64 * 64 * 8;                       // 32768
  const size_t proj_halfs = (size_t)n_nodes * HIDDEN;          // 12.8M
  const size_t need = (wpk_halfs + 2 * proj_halfs) * sizeof(_Float16);

  if (ws_size >= need) {
    _Float16* Wpk = (_Float16*)d_ws;
    _Float16* A   = Wpk + wpk_halfs;
    _Float16* B   = A + proj_halfs;

    prep_w<<<64, 64, 0, stream>>>(W1, Wpk);

    const int ntiles = (n_nodes + 15) / 16;       // 6250
    const int gblocks = ntiles < 1280 ? ntiles : 1280;
    gemm_mfma_v6<<<gblocks, 256, 0, stream>>>(h, Wpk, b1, A, B, n_nodes, ntiles);

    const int nwaves = (n_edges + 15) / 16;
    const int eblocks = (nwaves + 3) / 4;
    edge_score_v4<<<eblocks, 256, 0, stream>>>(ei, A, B, W2, b2, out, n_edges);
  } else {
    const int eblocks = (n_edges + 3) / 4;
    fused_fallback<<<eblocks, 256, 0, stream>>>(h, ei, W1, b1, W2, b2, out, n_edges);
  }
}

// Round 8
// 95.812 us; speedup vs baseline: 1.6147x; 1.3421x over previous
//
#include <hip/hip_runtime.h>

#define HIDDEN 128

typedef _Float16 f16x8 __attribute__((ext_vector_type(8)));
typedef _Float16 f16x4 __attribute__((ext_vector_type(4)));
typedef _Float16 f16x2 __attribute__((ext_vector_type(2)));
typedef __fp16   fp16v2 __attribute__((ext_vector_type(2)));  // builtin ABI type
typedef float f32x4 __attribute__((ext_vector_type(4)));

// ---------------------------------------------------------------------------
// Kernel 0: pack W1 (fp32, (256,128)) into fp16 MFMA fragments.
// Bmat (K=128, N=256): Bmat[k][n] = n<128 ? W1[k][n] : W1[128+k][n-128]
// Wpk[((jt*4+kt)*64 + lane)*8 + j] = Bmat[kt*32+(lane>>4)*8+j][jt*16+(lane&15)]
// Serves as A-operand fragment (A = Bmat^T): lane holds A[lane&15][(lane>>4)*8+j].
// ---------------------------------------------------------------------------
__global__ __launch_bounds__(64) void prep_w(const float* __restrict__ W1,
                                             _Float16* __restrict__ Wpk) {
  const int blk = blockIdx.x;        // 0..63 = jt*4 + kt
  const int jt = blk >> 2;
  const int kt = blk & 3;
  const int lane = threadIdx.x;      // 0..63
  const int col = jt * 16 + (lane & 15);         // feature 0..255
  const int kbase = kt * 32 + (lane >> 4) * 8;   // 0..120
  f16x8 v;
#pragma unroll
  for (int j = 0; j < 8; ++j) {
    const int k = kbase + j;
    const float w = (col < HIDDEN) ? W1[k * HIDDEN + col]
                                   : W1[(HIDDEN + k) * HIDDEN + (col - HIDDEN)];
    v[j] = (_Float16)w;
  }
  *reinterpret_cast<f16x8*>(Wpk + ((size_t)blk * 64 + lane) * 8) = v;
}

// ---------------------------------------------------------------------------
// Kernel 1 (v7): persistent grid-stride MFMA GEMM, depth-1 prefetch.
// launch_bounds(256,3): the ONLY no-spill bound found (v5/v6 post-mortem:
// (256,4)->64 VGPR and (256,5)->48 VGPR both spilled ~160-350MB to scratch).
// Occupancy comes from the GRID instead: 1280 blocks = 5/CU = 5 waves/SIMD
// (actual VGPR ~84 allows 6), vs 768 blocks = 24% in round 4.
// D[feat][node] = Wt @ h^T per 16-node tile; W-fragments + bias in VGPRs.
// ---------------------------------------------------------------------------
__global__ __launch_bounds__(256, 3) void gemm_mfma_v7(
    const float* __restrict__ h, const _Float16* __restrict__ Wpk,
    const float* __restrict__ b1, _Float16* __restrict__ Af,
    _Float16* __restrict__ Bf, int n_nodes, int ntiles) {
  const int lane = threadIdx.x & 63;
  const int wave = threadIdx.x >> 6;
  const int nl = lane & 15;
  const int kgrp = lane >> 4;
  const int jt0 = wave * 4;

  // Persistent W fragments: 16 x f16x8 (64 VGPRs), L2-resident source.
  const f16x8* wp = reinterpret_cast<const f16x8*>(Wpk);
  f16x8 wfrag[4][4];
#pragma unroll
  for (int j4 = 0; j4 < 4; ++j4)
#pragma unroll
    for (int kt = 0; kt < 4; ++kt)
      wfrag[j4][kt] = wp[((jt0 + j4) * 4 + kt) * 64 + lane];

  // Persistent bias (A-half only).
  f32x4 binit[4];
#pragma unroll
  for (int j4 = 0; j4 < 4; ++j4) {
    const int jt = jt0 + j4;
    if (jt < 8) {
      binit[j4] = *reinterpret_cast<const f32x4*>(b1 + jt * 16 + kgrp * 4);
    } else {
      binit[j4][0] = 0.f; binit[j4][1] = 0.f; binit[j4][2] = 0.f; binit[j4][3] = 0.f;
    }
  }

  float4 buf[8];     // raw fp32 loads for the NEXT tile (in flight)
  f16x8 hfrag[4];    // converted fragments for the CURRENT tile

  auto LOAD = [&](int tile) {
    int node = tile * 16 + nl;
    if (node >= n_nodes) node = 0;  // clamp; stores are guarded
    const float4* hp = reinterpret_cast<const float4*>(h) +
                       (size_t)node * 32 + kgrp * 2;
#pragma unroll
    for (int kt = 0; kt < 4; ++kt) {
      buf[kt * 2]     = hp[kt * 8];
      buf[kt * 2 + 1] = hp[kt * 8 + 1];
    }
  };

  auto CVT = [&]() {
#pragma unroll
    for (int kt = 0; kt < 4; ++kt) {
      const float4 v0 = buf[kt * 2];
      const float4 v1 = buf[kt * 2 + 1];
      const fp16v2 p0 = __builtin_amdgcn_cvt_pkrtz(v0.x, v0.y);
      const fp16v2 p1 = __builtin_amdgcn_cvt_pkrtz(v0.z, v0.w);
      const fp16v2 p2 = __builtin_amdgcn_cvt_pkrtz(v1.x, v1.y);
      const fp16v2 p3 = __builtin_amdgcn_cvt_pkrtz(v1.z, v1.w);
      hfrag[kt][0] = (_Float16)p0[0]; hfrag[kt][1] = (_Float16)p0[1];
      hfrag[kt][2] = (_Float16)p1[0]; hfrag[kt][3] = (_Float16)p1[1];
      hfrag[kt][4] = (_Float16)p2[0]; hfrag[kt][5] = (_Float16)p2[1];
      hfrag[kt][6] = (_Float16)p3[0]; hfrag[kt][7] = (_Float16)p3[1];
    }
  };

  auto COMPUTE_STORE = [&](int tile) {
    f32x4 acc[4];
#pragma unroll
    for (int j4 = 0; j4 < 4; ++j4) acc[j4] = binit[j4];
#pragma unroll
    for (int kt = 0; kt < 4; ++kt)
#pragma unroll
      for (int j4 = 0; j4 < 4; ++j4)
        acc[j4] = __builtin_amdgcn_mfma_f32_16x16x32_f16(
            wfrag[j4][kt], hfrag[kt], acc[j4], 0, 0, 0);
    const int node = tile * 16 + nl;
    if (node < n_nodes) {
#pragma unroll
      for (int j4 = 0; j4 < 4; ++j4) {
        const int jt = jt0 + j4;
        _Float16* dst = ((jt < 8) ? Af : Bf) +
                        (size_t)node * HIDDEN + (jt & 7) * 16 + kgrp * 4;
        f16x4 v;
        v[0] = (_Float16)acc[j4][0];
        v[1] = (_Float16)acc[j4][1];
        v[2] = (_Float16)acc[j4][2];
        v[3] = (_Float16)acc[j4][3];
        *reinterpret_cast<f16x4*>(dst) = v;
      }
    }
  };

  const int stride = gridDim.x;
  int tile = blockIdx.x;
  if (tile >= ntiles) return;

  LOAD(tile);
  CVT();
  int next = tile + stride;
  if (next < ntiles) LOAD(next);

  while (true) {
    COMPUTE_STORE(tile);
    if (next >= ntiles) break;
    CVT();
    const int next2 = next + stride;
    if (next2 < ntiles) LOAD(next2);
    tile = next;
    next = next2;
  }
}

// ---------------------------------------------------------------------------
// Kernel 2 (v4): per edge, score = relu(A[src] + B[dst]) . W2 + b2
// One wave per 16 edges; lane i holds f16x2 (4B) of each 256B row.
// 32-bit offsets (1 VALU addr/load), packed fp16 add/relu + fdot2.
// Merged butterfly reduction: lanes 0..15 end with the 16 edge scores.
// ---------------------------------------------------------------------------
__global__ __launch_bounds__(256) void edge_score_v4(
    const int* __restrict__ ei, const _Float16* __restrict__ Af,
    const _Float16* __restrict__ Bf, const float* __restrict__ W2,
    const float* __restrict__ b2, float* __restrict__ out, int n_edges) {
  const int wid = (int)((blockIdx.x * 256 + threadIdx.x) >> 6);
  const int lane = threadIdx.x & 63;
  const int e0 = wid * 16;
  if (e0 >= n_edges) return;

  int srcs[16], dsts[16];
#pragma unroll
  for (int k = 0; k < 16; ++k) {
    srcs[k] = ei[e0 + k];
    dsts[k] = ei[n_edges + e0 + k];
  }

  const char* Afc = (const char*)Af;
  const char* Bfc = (const char*)Bf;
  const unsigned int loff = (unsigned int)(lane << 2);

  f16x2 av[16], bv[16];
#pragma unroll
  for (int k = 0; k < 16; ++k) {
    const unsigned int off = ((unsigned int)srcs[k] << 8) + loff;
    av[k] = *reinterpret_cast<const f16x2*>(Afc + off);
  }
#pragma unroll
  for (int k = 0; k < 16; ++k) {
    const unsigned int off = ((unsigned int)dsts[k] << 8) + loff;
    bv[k] = *reinterpret_cast<const f16x2*>(Bfc + off);
  }

  const float2 w2v = reinterpret_cast<const float2*>(W2)[lane];
  const fp16v2 w2h = __builtin_amdgcn_cvt_pkrtz(w2v.x, w2v.y);
  const _Float16 h0 = (_Float16)0.f;

  float p[16];
#pragma unroll
  for (int k = 0; k < 16; ++k) {
    f16x2 s = av[k] + bv[k];                 // v_pk_add_f16
    s[0] = s[0] > h0 ? s[0] : h0;            // pk max vs 0
    s[1] = s[1] > h0 ? s[1] : h0;
    p[k] = __builtin_amdgcn_fdot2(__builtin_bit_cast(fp16v2, s), w2h, 0.f, false);
  }

  auto mrg = [&](float a, float b, int off) {
    const float as = a + __shfl_xor(a, off, 64);
    const float bs = b + __shfl_xor(b, off, 64);
    return (lane & off) ? bs : as;
  };
  float q[8];
#pragma unroll
  for (int i = 0; i < 8; ++i) q[i] = mrg(p[2 * i], p[2 * i + 1], 1);
  float r[4];
#pragma unroll
  for (int i = 0; i < 4; ++i) r[i] = mrg(q[2 * i], q[2 * i + 1], 2);
  float s2[2];
#pragma unroll
  for (int i = 0; i < 2; ++i) s2[i] = mrg(r[2 * i], r[2 * i + 1], 4);
  float t = mrg(s2[0], s2[1], 8);
  t += __shfl_xor(t, 16, 64);
  t += __shfl_xor(t, 32, 64);

  if (lane < 16 && e0 + lane < n_edges) out[e0 + lane] = t + b2[0];
}

// ---------------------------------------------------------------------------
// Fallback (ws too small): fused fp32 per-edge compute.
// ---------------------------------------------------------------------------
__global__ __launch_bounds__(256) void fused_fallback(
    const float* __restrict__ h, const int* __restrict__ ei,
    const float* __restrict__ W1, const float* __restrict__ b1,
    const float* __restrict__ W2, const float* __restrict__ b2,
    float* __restrict__ out, int n_edges) {
  const int e = (int)((blockIdx.x * 256 + threadIdx.x) >> 6);
  const int lane = threadIdx.x & 63;
  if (e >= n_edges) return;
  const int src = ei[e], dst = ei[n_edges + e];
  const float* hs = h + (size_t)src * HIDDEN;
  const float* hd = h + (size_t)dst * HIDDEN;
  float acc0 = b1[lane], acc1 = b1[lane + 64];
  for (int k = 0; k < HIDDEN; ++k) {
    const float s = hs[k], d = hd[k];
    acc0 = fmaf(s, W1[k * HIDDEN + lane], acc0);
    acc0 = fmaf(d, W1[(k + HIDDEN) * HIDDEN + lane], acc0);
    acc1 = fmaf(s, W1[k * HIDDEN + lane + 64], acc1);
    acc1 = fmaf(d, W1[(k + HIDDEN) * HIDDEN + lane + 64], acc1);
  }
  acc0 = acc0 > 0.f ? acc0 : 0.f;
  acc1 = acc1 > 0.f ? acc1 : 0.f;
  float p = fmaf(acc0, W2[lane], acc1 * W2[lane + 64]);
#pragma unroll
  for (int off = 32; off >= 1; off >>= 1) p += __shfl_down(p, off, 64);
  if (lane == 0) out[e] = p + b2[0];
}

extern "C" void kernel_launch(void* const* d_in, const int* in_sizes, int n_in,
                              void* d_out, int out_size, void* d_ws, size_t ws_size,
                              hipStream_t stream) {
  const float* h  = (const float*)d_in[0];
  const int*   ei = (const int*)d_in[1];
  const float* W1 = (const float*)d_in[2];
  const float* b1 = (const float*)d_in[3];
  const float* W2 = (const float*)d_in[4];
  const float* b2 = (const float*)d_in[5];
  float* out = (float*)d_out;

  const int n_nodes = in_sizes[0] / HIDDEN;  // 100000
  const int n_edges = in_sizes[1] / 2;       // 640000

  const size_t wpk_halfs  = 64 * 64 * 8;                       // 32768
  const size_t proj_halfs = (size_t)n_nodes * HIDDEN;          // 12.8M
  const size_t need = (wpk_halfs + 2 * proj_halfs) * sizeof(_Float16);

  if (ws_size >= need) {
    _Float16* Wpk = (_Float16*)d_ws;
    _Float16* A   = Wpk + wpk_halfs;
    _Float16* B   = A + proj_halfs;

    prep_w<<<64, 64, 0, stream>>>(W1, Wpk);

    const int ntiles = (n_nodes + 15) / 16;       // 6250
    const int gblocks = ntiles < 1280 ? ntiles : 1280;
    gemm_mfma_v7<<<gblocks, 256, 0, stream>>>(h, Wpk, b1, A, B, n_nodes, ntiles);

    const int nwaves = (n_edges + 15) / 16;
    const int eblocks = (nwaves + 3) / 4;
    edge_score_v4<<<eblocks, 256, 0, stream>>>(ei, A, B, W2, b2, out, n_edges);
  } else {
    const int eblocks = (n_edges + 3) / 4;
    fused_fallback<<<eblocks, 256, 0, stream>>>(h, ei, W1, b1, W2, b2, out, n_edges);
  }
}

// Round 9
// 88.649 us; speedup vs baseline: 1.7451x; 1.0808x over previous
//
#include <hip/hip_runtime.h>

#define HIDDEN 128

typedef _Float16 f16x8 __attribute__((ext_vector_type(8)));
typedef _Float16 f16x4 __attribute__((ext_vector_type(4)));
typedef _Float16 f16x2 __attribute__((ext_vector_type(2)));
typedef __fp16   fp16v2 __attribute__((ext_vector_type(2)));  // builtin ABI type
typedef float f32x4 __attribute__((ext_vector_type(4)));

// ---------------------------------------------------------------------------
// Kernel 0: pack W1 (fp32, (256,128)) into fp16 MFMA fragments.
// Bmat (K=128, N=256): Bmat[k][n] = n<128 ? W1[k][n] : W1[128+k][n-128]
// Wpk[((jt*4+kt)*64 + lane)*8 + j] = Bmat[kt*32+(lane>>4)*8+j][jt*16+(lane&15)]
// Serves as A-operand fragment (A = Bmat^T): lane holds A[lane&15][(lane>>4)*8+j].
// ---------------------------------------------------------------------------
__global__ __launch_bounds__(64) void prep_w(const float* __restrict__ W1,
                                             _Float16* __restrict__ Wpk) {
  const int blk = blockIdx.x;        // 0..63 = jt*4 + kt
  const int jt = blk >> 2;
  const int kt = blk & 3;
  const int lane = threadIdx.x;      // 0..63
  const int col = jt * 16 + (lane & 15);         // feature 0..255
  const int kbase = kt * 32 + (lane >> 4) * 8;   // 0..120
  f16x8 v;
#pragma unroll
  for (int j = 0; j < 8; ++j) {
    const int k = kbase + j;
    const float w = (col < HIDDEN) ? W1[k * HIDDEN + col]
                                   : W1[(HIDDEN + k) * HIDDEN + (col - HIDDEN)];
    v[j] = (_Float16)w;
  }
  *reinterpret_cast<f16x8*>(Wpk + ((size_t)blk * 64 + lane) * 8) = v;
}

// ---------------------------------------------------------------------------
// Kernel 1 (v8): v7 + LDS-bounce epilogue for coalesced stores.
// v7 post-mortem: dur was occupancy-INDEPENDENT (7% vs 21% -> same 51us) ->
// bound by per-CU L2 transaction rate from the 8B/256B-stride store scatter
// (~1024 tx/tile). Fix: acc -> LDS (padded rows, 2-way conflicts = free),
// barrier, coalesced 16B-dense copy-out (~128 tx/tile).
// launch_bounds(256,3) = the known no-spill bound; grid 1280.
// ---------------------------------------------------------------------------
__global__ __launch_bounds__(256, 3) void gemm_mfma_v8(
    const float* __restrict__ h, const _Float16* __restrict__ Wpk,
    const float* __restrict__ b1, _Float16* __restrict__ Af,
    _Float16* __restrict__ Bf, int n_nodes, int ntiles) {
  // 16 nodes x 512B of fp16 feats (Af half then Bf half), +16B pad per row.
  __shared__ __align__(16) char out_lds[16 * 528];

  const int tid = threadIdx.x;
  const int lane = tid & 63;
  const int wave = tid >> 6;
  const int nl = lane & 15;
  const int kgrp = lane >> 4;
  const int jt0 = wave * 4;

  // Persistent W fragments: 16 x f16x8 (64 VGPRs), L2-resident source.
  const f16x8* wp = reinterpret_cast<const f16x8*>(Wpk);
  f16x8 wfrag[4][4];
#pragma unroll
  for (int j4 = 0; j4 < 4; ++j4)
#pragma unroll
    for (int kt = 0; kt < 4; ++kt)
      wfrag[j4][kt] = wp[((jt0 + j4) * 4 + kt) * 64 + lane];

  // Persistent bias (A-half only).
  f32x4 binit[4];
#pragma unroll
  for (int j4 = 0; j4 < 4; ++j4) {
    const int jt = jt0 + j4;
    if (jt < 8) {
      binit[j4] = *reinterpret_cast<const f32x4*>(b1 + jt * 16 + kgrp * 4);
    } else {
      binit[j4][0] = 0.f; binit[j4][1] = 0.f; binit[j4][2] = 0.f; binit[j4][3] = 0.f;
    }
  }

  float4 buf[8];     // raw fp32 loads for the NEXT tile (in flight)
  f16x8 hfrag[4];    // converted fragments for the CURRENT tile

  auto LOAD = [&](int tile) {
    int node = tile * 16 + nl;
    if (node >= n_nodes) node = 0;  // clamp; copy-out is guarded
    const float4* hp = reinterpret_cast<const float4*>(h) +
                       (size_t)node * 32 + kgrp * 2;
#pragma unroll
    for (int kt = 0; kt < 4; ++kt) {
      buf[kt * 2]     = hp[kt * 8];
      buf[kt * 2 + 1] = hp[kt * 8 + 1];
    }
  };

  auto CVT = [&]() {
#pragma unroll
    for (int kt = 0; kt < 4; ++kt) {
      const float4 v0 = buf[kt * 2];
      const float4 v1 = buf[kt * 2 + 1];
      const fp16v2 p0 = __builtin_amdgcn_cvt_pkrtz(v0.x, v0.y);
      const fp16v2 p1 = __builtin_amdgcn_cvt_pkrtz(v0.z, v0.w);
      const fp16v2 p2 = __builtin_amdgcn_cvt_pkrtz(v1.x, v1.y);
      const fp16v2 p3 = __builtin_amdgcn_cvt_pkrtz(v1.z, v1.w);
      hfrag[kt][0] = (_Float16)p0[0]; hfrag[kt][1] = (_Float16)p0[1];
      hfrag[kt][2] = (_Float16)p1[0]; hfrag[kt][3] = (_Float16)p1[1];
      hfrag[kt][4] = (_Float16)p2[0]; hfrag[kt][5] = (_Float16)p2[1];
      hfrag[kt][6] = (_Float16)p3[0]; hfrag[kt][7] = (_Float16)p3[1];
    }
  };

  // MFMA into acc, then scatter acc into LDS (ds_write_b64; padded rows ->
  // 2-way bank aliasing only, which is free on CDNA4).
  auto COMPUTE_DSWRITE = [&]() {
    f32x4 acc[4];
#pragma unroll
    for (int j4 = 0; j4 < 4; ++j4) acc[j4] = binit[j4];
#pragma unroll
    for (int kt = 0; kt < 4; ++kt)
#pragma unroll
      for (int j4 = 0; j4 < 4; ++j4)
        acc[j4] = __builtin_amdgcn_mfma_f32_16x16x32_f16(
            wfrag[j4][kt], hfrag[kt], acc[j4], 0, 0, 0);
#pragma unroll
    for (int j4 = 0; j4 < 4; ++j4) {
      const int jt = jt0 + j4;
      const int byte = nl * 528 + ((jt & 7) * 16 + kgrp * 4) * 2 +
                       ((jt >= 8) ? 256 : 0);
      f16x4 v;
      v[0] = (_Float16)acc[j4][0];
      v[1] = (_Float16)acc[j4][1];
      v[2] = (_Float16)acc[j4][2];
      v[3] = (_Float16)acc[j4][3];
      *reinterpret_cast<f16x4*>(out_lds + byte) = v;
    }
  };

  // Coalesced copy-out: thread t -> node t>>4, 16B segment t&15.
  // Per wave-inst: 4 nodes x 256B dense -> full-line 16B stores.
  const int cn = tid >> 4;        // local node 0..15
  const int seg = tid & 15;       // 16B segment within the 256B half-row
  auto COPYOUT = [&](int tile) {
    const int node = tile * 16 + cn;
    if (node < n_nodes) {
      const f16x8 a = *reinterpret_cast<const f16x8*>(out_lds + cn * 528 + seg * 16);
      const f16x8 b = *reinterpret_cast<const f16x8*>(out_lds + cn * 528 + 256 + seg * 16);
      *reinterpret_cast<f16x8*>(Af + (size_t)node * HIDDEN + seg * 8) = a;
      *reinterpret_cast<f16x8*>(Bf + (size_t)node * HIDDEN + seg * 8) = b;
    }
  };

  const int stride = gridDim.x;
  int tile = blockIdx.x;
  if (tile >= ntiles) return;

  LOAD(tile);
  CVT();
  int next = tile + stride;
  if (next < ntiles) LOAD(next);

  while (true) {
    COMPUTE_DSWRITE();            // MFMA on hfrag(t), acc -> LDS
    if (next < ntiles) CVT();     // wait + convert buf(t+1) while LDS settles
    __syncthreads();              // out_lds complete
    COPYOUT(tile);                // coalesced stores
    if (next >= ntiles) break;
    const int next2 = next + stride;
    if (next2 < ntiles) LOAD(next2);
    __syncthreads();              // out_lds consumed; safe to overwrite
    tile = next;
    next = next2;
  }
}

// ---------------------------------------------------------------------------
// Kernel 2 (v4): per edge, score = relu(A[src] + B[dst]) . W2 + b2
// One wave per 16 edges; lane i holds f16x2 (4B) of each 256B row.
// 32-bit offsets (1 VALU addr/load), packed fp16 add/relu + fdot2.
// Merged butterfly reduction: lanes 0..15 end with the 16 edge scores.
// ---------------------------------------------------------------------------
__global__ __launch_bounds__(256) void edge_score_v4(
    const int* __restrict__ ei, const _Float16* __restrict__ Af,
    const _Float16* __restrict__ Bf, const float* __restrict__ W2,
    const float* __restrict__ b2, float* __restrict__ out, int n_edges) {
  const int wid = (int)((blockIdx.x * 256 + threadIdx.x) >> 6);
  const int lane = threadIdx.x & 63;
  const int e0 = wid * 16;
  if (e0 >= n_edges) return;

  int srcs[16], dsts[16];
#pragma unroll
  for (int k = 0; k < 16; ++k) {
    srcs[k] = ei[e0 + k];
    dsts[k] = ei[n_edges + e0 + k];
  }

  const char* Afc = (const char*)Af;
  const char* Bfc = (const char*)Bf;
  const unsigned int loff = (unsigned int)(lane << 2);

  f16x2 av[16], bv[16];
#pragma unroll
  for (int k = 0; k < 16; ++k) {
    const unsigned int off = ((unsigned int)srcs[k] << 8) + loff;
    av[k] = *reinterpret_cast<const f16x2*>(Afc + off);
  }
#pragma unroll
  for (int k = 0; k < 16; ++k) {
    const unsigned int off = ((unsigned int)dsts[k] << 8) + loff;
    bv[k] = *reinterpret_cast<const f16x2*>(Bfc + off);
  }

  const float2 w2v = reinterpret_cast<const float2*>(W2)[lane];
  const fp16v2 w2h = __builtin_amdgcn_cvt_pkrtz(w2v.x, w2v.y);
  const _Float16 h0 = (_Float16)0.f;

  float p[16];
#pragma unroll
  for (int k = 0; k < 16; ++k) {
    f16x2 s = av[k] + bv[k];                 // v_pk_add_f16
    s[0] = s[0] > h0 ? s[0] : h0;            // pk max vs 0
    s[1] = s[1] > h0 ? s[1] : h0;
    p[k] = __builtin_amdgcn_fdot2(__builtin_bit_cast(fp16v2, s), w2h, 0.f, false);
  }

  auto mrg = [&](float a, float b, int off) {
    const float as = a + __shfl_xor(a, off, 64);
    const float bs = b + __shfl_xor(b, off, 64);
    return (lane & off) ? bs : as;
  };
  float q[8];
#pragma unroll
  for (int i = 0; i < 8; ++i) q[i] = mrg(p[2 * i], p[2 * i + 1], 1);
  float r[4];
#pragma unroll
  for (int i = 0; i < 4; ++i) r[i] = mrg(q[2 * i], q[2 * i + 1], 2);
  float s2[2];
#pragma unroll
  for (int i = 0; i < 2; ++i) s2[i] = mrg(r[2 * i], r[2 * i + 1], 4);
  float t = mrg(s2[0], s2[1], 8);
  t += __shfl_xor(t, 16, 64);
  t += __shfl_xor(t, 32, 64);

  if (lane < 16 && e0 + lane < n_edges) out[e0 + lane] = t + b2[0];
}

// ---------------------------------------------------------------------------
// Fallback (ws too small): fused fp32 per-edge compute.
// ---------------------------------------------------------------------------
__global__ __launch_bounds__(256) void fused_fallback(
    const float* __restrict__ h, const int* __restrict__ ei,
    const float* __restrict__ W1, const float* __restrict__ b1,
    const float* __restrict__ W2, const float* __restrict__ b2,
    float* __restrict__ out, int n_edges) {
  const int e = (int)((blockIdx.x * 256 + threadIdx.x) >> 6);
  const int lane = threadIdx.x & 63;
  if (e >= n_edges) return;
  const int src = ei[e], dst = ei[n_edges + e];
  const float* hs = h + (size_t)src * HIDDEN;
  const float* hd = h + (size_t)dst * HIDDEN;
  float acc0 = b1[lane], acc1 = b1[lane + 64];
  for (int k = 0; k < HIDDEN; ++k) {
    const float s = hs[k], d = hd[k];
    acc0 = fmaf(s, W1[k * HIDDEN + lane], acc0);
    acc0 = fmaf(d, W1[(k + HIDDEN) * HIDDEN + lane], acc0);
    acc1 = fmaf(s, W1[k * HIDDEN + lane + 64], acc1);
    acc1 = fmaf(d, W1[(k + HIDDEN) * HIDDEN + lane + 64], acc1);
  }
  acc0 = acc0 > 0.f ? acc0 : 0.f;
  acc1 = acc1 > 0.f ? acc1 : 0.f;
  float p = fmaf(acc0, W2[lane], acc1 * W2[lane + 64]);
#pragma unroll
  for (int off = 32; off >= 1; off >>= 1) p += __shfl_down(p, off, 64);
  if (lane == 0) out[e] = p + b2[0];
}

extern "C" void kernel_launch(void* const* d_in, const int* in_sizes, int n_in,
                              void* d_out, int out_size, void* d_ws, size_t ws_size,
                              hipStream_t stream) {
  const float* h  = (const float*)d_in[0];
  const int*   ei = (const int*)d_in[1];
  const float* W1 = (const float*)d_in[2];
  const float* b1 = (const float*)d_in[3];
  const float* W2 = (const float*)d_in[4];
  const float* b2 = (const float*)d_in[5];
  float* out = (float*)d_out;

  const int n_nodes = in_sizes[0] / HIDDEN;  // 100000
  const int n_edges = in_sizes[1] / 2;       // 640000

  const size_t wpk_halfs  = 64 * 64 * 8;                       // 32768
  const size_t proj_halfs = (size_t)n_nodes * HIDDEN;          // 12.8M
  const size_t need = (wpk_halfs + 2 * proj_halfs) * sizeof(_Float16);

  if (ws_size >= need) {
    _Float16* Wpk = (_Float16*)d_ws;
    _Float16* A   = Wpk + wpk_halfs;
    _Float16* B   = A + proj_halfs;

    prep_w<<<64, 64, 0, stream>>>(W1, Wpk);

    const int ntiles = (n_nodes + 15) / 16;       // 6250
    const int gblocks = ntiles < 1280 ? ntiles : 1280;
    gemm_mfma_v8<<<gblocks, 256, 0, stream>>>(h, Wpk, b1, A, B, n_nodes, ntiles);

    const int nwaves = (n_edges + 15) / 16;
    const int eblocks = (nwaves + 3) / 4;
    edge_score_v4<<<eblocks, 256, 0, stream>>>(ei, A, B, W2, b2, out, n_edges);
  } else {
    const int eblocks = (n_edges + 3) / 4;
    fused_fallback<<<eblocks, 256, 0, stream>>>(h, ei, W1, b1, W2, b2, out, n_edges);
  }
}

// Round 10
// 86.991 us; speedup vs baseline: 1.7784x; 1.0191x over previous
//
#include <hip/hip_runtime.h>

#define HIDDEN 128

typedef _Float16 f16x8 __attribute__((ext_vector_type(8)));
typedef _Float16 f16x4 __attribute__((ext_vector_type(4)));
typedef _Float16 f16x2 __attribute__((ext_vector_type(2)));
typedef __fp16   fp16v2 __attribute__((ext_vector_type(2)));  // builtin ABI type
typedef float f32x4 __attribute__((ext_vector_type(4)));

// ---------------------------------------------------------------------------
// Kernel 0: pack W1 (fp32, (256,128)) into fp16 MFMA fragments.
// Bmat (K=128, N=256): Bmat[k][n] = n<128 ? W1[k][n] : W1[128+k][n-128]
// Wpk[((jt*4+kt)*64 + lane)*8 + j] = Bmat[kt*32+(lane>>4)*8+j][jt*16+(lane&15)]
// Serves as A-operand fragment (A = Bmat^T): lane holds A[lane&15][(lane>>4)*8+j].
// ---------------------------------------------------------------------------
__global__ __launch_bounds__(64) void prep_w(const float* __restrict__ W1,
                                             _Float16* __restrict__ Wpk) {
  const int blk = blockIdx.x;        // 0..63 = jt*4 + kt
  const int jt = blk >> 2;
  const int kt = blk & 3;
  const int lane = threadIdx.x;      // 0..63
  const int col = jt * 16 + (lane & 15);         // feature 0..255
  const int kbase = kt * 32 + (lane >> 4) * 8;   // 0..120
  f16x8 v;
#pragma unroll
  for (int j = 0; j < 8; ++j) {
    const int k = kbase + j;
    const float w = (col < HIDDEN) ? W1[k * HIDDEN + col]
                                   : W1[(HIDDEN + k) * HIDDEN + (col - HIDDEN)];
    v[j] = (_Float16)w;
  }
  *reinterpret_cast<f16x8*>(Wpk + ((size_t)blk * 64 + lane) * 8) = v;
}

// ---------------------------------------------------------------------------
// Kernel 1 (v9): 4 tiles (64 consecutive nodes) per block, static depth-2
// pipeline, NO stores before any wait (v8 post-mortem: per-tile barrier/
// vmcnt(0) drains serialize on store-ack + load latency; every model says
// this kernel should be <10us of real work). All global stores issue once
// at the very end after a single barrier. No min-waves launch_bounds arg:
// every hint so far made the allocator jump a tier and spill.
// ---------------------------------------------------------------------------
__global__ __launch_bounds__(256) void gemm_mfma_v9(
    const float* __restrict__ h, const _Float16* __restrict__ Wpk,
    const float* __restrict__ b1, _Float16* __restrict__ Af,
    _Float16* __restrict__ Bf, int n_nodes, int ntiles) {
  // 4 tiles x 16 nodes x (512B feats + 16B pad).
  __shared__ __align__(16) char out_lds[4 * 16 * 528];

  const int tid = threadIdx.x;
  const int lane = tid & 63;
  const int wave = tid >> 6;
  const int nl = lane & 15;
  const int kgrp = lane >> 4;
  const int jt0 = wave * 4;
  const int t0 = blockIdx.x * 4;
  if (t0 >= ntiles) return;

  // Persistent W fragments: 16 x f16x8 (64 VGPRs), L2-resident source.
  const f16x8* wp = reinterpret_cast<const f16x8*>(Wpk);
  f16x8 wfrag[4][4];
#pragma unroll
  for (int j4 = 0; j4 < 4; ++j4)
#pragma unroll
    for (int kt = 0; kt < 4; ++kt)
      wfrag[j4][kt] = wp[((jt0 + j4) * 4 + kt) * 64 + lane];

  // Bias (A-half only).
  f32x4 binit[4];
#pragma unroll
  for (int j4 = 0; j4 < 4; ++j4) {
    const int jt = jt0 + j4;
    if (jt < 8) {
      binit[j4] = *reinterpret_cast<const f32x4*>(b1 + jt * 16 + kgrp * 4);
    } else {
      binit[j4][0] = 0.f; binit[j4][1] = 0.f; binit[j4][2] = 0.f; binit[j4][3] = 0.f;
    }
  }

  float4 buf0[8], buf1[8];   // two in-flight tile buffers (static names)
  f16x8 hfrag[4];

  auto LOAD = [&](float4* buf, int tile) {
    int node = tile * 16 + nl;
    if (node >= n_nodes) node = 0;  // clamp; copy-out is guarded
    const float4* hp = reinterpret_cast<const float4*>(h) +
                       (size_t)node * 32 + kgrp * 2;
#pragma unroll
    for (int kt = 0; kt < 4; ++kt) {
      buf[kt * 2]     = hp[kt * 8];
      buf[kt * 2 + 1] = hp[kt * 8 + 1];
    }
  };

  auto CVT = [&](const float4* buf) {
#pragma unroll
    for (int kt = 0; kt < 4; ++kt) {
      const float4 v0 = buf[kt * 2];
      const float4 v1 = buf[kt * 2 + 1];
      const fp16v2 p0 = __builtin_amdgcn_cvt_pkrtz(v0.x, v0.y);
      const fp16v2 p1 = __builtin_amdgcn_cvt_pkrtz(v0.z, v0.w);
      const fp16v2 p2 = __builtin_amdgcn_cvt_pkrtz(v1.x, v1.y);
      const fp16v2 p3 = __builtin_amdgcn_cvt_pkrtz(v1.z, v1.w);
      hfrag[kt][0] = (_Float16)p0[0]; hfrag[kt][1] = (_Float16)p0[1];
      hfrag[kt][2] = (_Float16)p1[0]; hfrag[kt][3] = (_Float16)p1[1];
      hfrag[kt][4] = (_Float16)p2[0]; hfrag[kt][5] = (_Float16)p2[1];
      hfrag[kt][6] = (_Float16)p3[0]; hfrag[kt][7] = (_Float16)p3[1];
    }
  };

  // MFMA on hfrag, convert acc to fp16, park in LDS (no global traffic).
  auto COMPUTE_DSWRITE = [&](int i) {
    f32x4 acc[4];
#pragma unroll
    for (int j4 = 0; j4 < 4; ++j4) acc[j4] = binit[j4];
#pragma unroll
    for (int kt = 0; kt < 4; ++kt)
#pragma unroll
      for (int j4 = 0; j4 < 4; ++j4)
        acc[j4] = __builtin_amdgcn_mfma_f32_16x16x32_f16(
            wfrag[j4][kt], hfrag[kt], acc[j4], 0, 0, 0);
#pragma unroll
    for (int j4 = 0; j4 < 4; ++j4) {
      const int jt = jt0 + j4;
      const int byte = i * 8448 + nl * 528 +
                       ((jt & 7) * 16 + kgrp * 4) * 2 + ((jt >= 8) ? 256 : 0);
      f16x4 v;
      v[0] = (_Float16)acc[j4][0];
      v[1] = (_Float16)acc[j4][1];
      v[2] = (_Float16)acc[j4][2];
      v[3] = (_Float16)acc[j4][3];
      *reinterpret_cast<f16x4*>(out_lds + byte) = v;
    }
  };

  // Static depth-2 pipeline over 4 tiles; the only waits are counted-vmcnt
  // for the buffer being converted. Zero stores issued in this region.
  LOAD(buf0, t0);
  LOAD(buf1, t0 + 1);
  CVT(buf0); LOAD(buf0, t0 + 2); COMPUTE_DSWRITE(0);
  CVT(buf1); LOAD(buf1, t0 + 3); COMPUTE_DSWRITE(1);
  CVT(buf0);                     COMPUTE_DSWRITE(2);
  CVT(buf1);                     COMPUTE_DSWRITE(3);

  __syncthreads();  // nothing outstanding but consumed loads + LDS writes

  // Coalesced copy-out: thread t -> node t>>4, 16B segment t&15; 8 dense
  // 16B stores per thread, all fire-and-forget until kernel retire.
  const int cn = tid >> 4;
  const int seg = tid & 15;
#pragma unroll
  for (int i = 0; i < 4; ++i) {
    const int node = (t0 + i) * 16 + cn;
    if (node < n_nodes) {
      const f16x8 a = *reinterpret_cast<const f16x8*>(
          out_lds + i * 8448 + cn * 528 + seg * 16);
      const f16x8 b = *reinterpret_cast<const f16x8*>(
          out_lds + i * 8448 + cn * 528 + 256 + seg * 16);
      *reinterpret_cast<f16x8*>(Af + (size_t)node * HIDDEN + seg * 8) = a;
      *reinterpret_cast<f16x8*>(Bf + (size_t)node * HIDDEN + seg * 8) = b;
    }
  }
}

// ---------------------------------------------------------------------------
// Kernel 2 (v4): per edge, score = relu(A[src] + B[dst]) . W2 + b2
// One wave per 16 edges; lane i holds f16x2 (4B) of each 256B row.
// 32-bit offsets, packed fp16 add/relu + fdot2, merged butterfly reduction.
// ---------------------------------------------------------------------------
__global__ __launch_bounds__(256) void edge_score_v4(
    const int* __restrict__ ei, const _Float16* __restrict__ Af,
    const _Float16* __restrict__ Bf, const float* __restrict__ W2,
    const float* __restrict__ b2, float* __restrict__ out, int n_edges) {
  const int wid = (int)((blockIdx.x * 256 + threadIdx.x) >> 6);
  const int lane = threadIdx.x & 63;
  const int e0 = wid * 16;
  if (e0 >= n_edges) return;

  int srcs[16], dsts[16];
#pragma unroll
  for (int k = 0; k < 16; ++k) {
    srcs[k] = ei[e0 + k];
    dsts[k] = ei[n_edges + e0 + k];
  }

  const char* Afc = (const char*)Af;
  const char* Bfc = (const char*)Bf;
  const unsigned int loff = (unsigned int)(lane << 2);

  f16x2 av[16], bv[16];
#pragma unroll
  for (int k = 0; k < 16; ++k) {
    const unsigned int off = ((unsigned int)srcs[k] << 8) + loff;
    av[k] = *reinterpret_cast<const f16x2*>(Afc + off);
  }
#pragma unroll
  for (int k = 0; k < 16; ++k) {
    const unsigned int off = ((unsigned int)dsts[k] << 8) + loff;
    bv[k] = *reinterpret_cast<const f16x2*>(Bfc + off);
  }

  const float2 w2v = reinterpret_cast<const float2*>(W2)[lane];
  const fp16v2 w2h = __builtin_amdgcn_cvt_pkrtz(w2v.x, w2v.y);
  const _Float16 h0 = (_Float16)0.f;

  float p[16];
#pragma unroll
  for (int k = 0; k < 16; ++k) {
    f16x2 s = av[k] + bv[k];                 // v_pk_add_f16
    s[0] = s[0] > h0 ? s[0] : h0;            // pk max vs 0
    s[1] = s[1] > h0 ? s[1] : h0;
    p[k] = __builtin_amdgcn_fdot2(__builtin_bit_cast(fp16v2, s), w2h, 0.f, false);
  }

  auto mrg = [&](float a, float b, int off) {
    const float as = a + __shfl_xor(a, off, 64);
    const float bs = b + __shfl_xor(b, off, 64);
    return (lane & off) ? bs : as;
  };
  float q[8];
#pragma unroll
  for (int i = 0; i < 8; ++i) q[i] = mrg(p[2 * i], p[2 * i + 1], 1);
  float r[4];
#pragma unroll
  for (int i = 0; i < 4; ++i) r[i] = mrg(q[2 * i], q[2 * i + 1], 2);
  float s2[2];
#pragma unroll
  for (int i = 0; i < 2; ++i) s2[i] = mrg(r[2 * i], r[2 * i + 1], 4);
  float t = mrg(s2[0], s2[1], 8);
  t += __shfl_xor(t, 16, 64);
  t += __shfl_xor(t, 32, 64);

  if (lane < 16 && e0 + lane < n_edges) out[e0 + lane] = t + b2[0];
}

// ---------------------------------------------------------------------------
// Fallback (ws too small): fused fp32 per-edge compute.
// ---------------------------------------------------------------------------
__global__ __launch_bounds__(256) void fused_fallback(
    const float* __restrict__ h, const int* __restrict__ ei,
    const float* __restrict__ W1, const float* __restrict__ b1,
    const float* __restrict__ W2, const float* __restrict__ b2,
    float* __restrict__ out, int n_edges) {
  const int e = (int)((blockIdx.x * 256 + threadIdx.x) >> 6);
  const int lane = threadIdx.x & 63;
  if (e >= n_edges) return;
  const int src = ei[e], dst = ei[n_edges + e];
  const float* hs = h + (size_t)src * HIDDEN;
  const float* hd = h + (size_t)dst * HIDDEN;
  float acc0 = b1[lane], acc1 = b1[lane + 64];
  for (int k = 0; k < HIDDEN; ++k) {
    const float s = hs[k], d = hd[k];
    acc0 = fmaf(s, W1[k * HIDDEN + lane], acc0);
    acc0 = fmaf(d, W1[(k + HIDDEN) * HIDDEN + lane], acc0);
    acc1 = fmaf(s, W1[k * HIDDEN + lane + 64], acc1);
    acc1 = fmaf(d, W1[(k + HIDDEN) * HIDDEN + lane + 64], acc1);
  }
  acc0 = acc0 > 0.f ? acc0 : 0.f;
  acc1 = acc1 > 0.f ? acc1 : 0.f;
  float p = fmaf(acc0, W2[lane], acc1 * W2[lane + 64]);
#pragma unroll
  for (int off = 32; off >= 1; off >>= 1) p += __shfl_down(p, off, 64);
  if (lane == 0) out[e] = p + b2[0];
}

extern "C" void kernel_launch(void* const* d_in, const int* in_sizes, int n_in,
                              void* d_out, int out_size, void* d_ws, size_t ws_size,
                              hipStream_t stream) {
  const float* h  = (const float*)d_in[0];
  const int*   ei = (const int*)d_in[1];
  const float* W1 = (const float*)d_in[2];
  const float* b1 = (const float*)d_in[3];
  const float* W2 = (const float*)d_in[4];
  const float* b2 = (const float*)d_in[5];
  float* out = (float*)d_out;

  const int n_nodes = in_sizes[0] / HIDDEN;  // 100000
  const int n_edges = in_sizes[1] / 2;       // 640000

  const size_t wpk_halfs  = 64 * 64 * 8;                       // 32768
  const size_t proj_halfs = (size_t)n_nodes * HIDDEN;          // 12.8M
  const size_t need = (wpk_halfs + 2 * proj_halfs) * sizeof(_Float16);

  if (ws_size >= need) {
    _Float16* Wpk = (_Float16*)d_ws;
    _Float16* A   = Wpk + wpk_halfs;
    _Float16* B   = A + proj_halfs;

    prep_w<<<64, 64, 0, stream>>>(W1, Wpk);

    const int ntiles = (n_nodes + 15) / 16;       // 6250
    const int gblocks = (ntiles + 3) / 4;         // 1563
    gemm_mfma_v9<<<gblocks, 256, 0, stream>>>(h, Wpk, b1, A, B, n_nodes, ntiles);

    const int nwaves = (n_edges + 15) / 16;
    const int eblocks = (nwaves + 3) / 4;
    edge_score_v4<<<eblocks, 256, 0, stream>>>(ei, A, B, W2, b2, out, n_edges);
  } else {
    const int eblocks = (n_edges + 3) / 4;
    fused_fallback<<<eblocks, 256, 0, stream>>>(h, ei, W1, b1, W2, b2, out, n_edges);
  }
}